// Round 2
// baseline (624.094 us; speedup 1.0000x reference)
//
#include <hip/hip_runtime.h>
#include <hip/hip_bf16.h>

// LSTM decoder: B=2048, L=64, H=128, O=64, T=512.  Output: FLOAT32 [B,T,O].
// Identity: next input x == h  =>  t>=1: gates = h @ (W_ih+W_hh)^T + (b_ih+b_hh)
//           t==0 (x=0):             gates = h0 @ W_hh^T + (b_ih+b_hh)
// One WG per 8 batch rows (256 WGs = 1/CU), recurrent weights register-resident
// as SPLIT bf16 (hi+lo) MFMA B-fragments for ~2^-17 effective precision,
// h kept split in 2x4KB XOR-swizzled LDS, cell state c in fp32 registers.

#define H_DIM 128
#define L_DIM 64
#define O_DIM 64
#define ROWS 8
#define THREADS 512

typedef __attribute__((ext_vector_type(4))) float f32x4;
typedef __attribute__((ext_vector_type(4))) float float4v;
typedef __attribute__((ext_vector_type(8))) __bf16 bf16x8;
typedef __attribute__((ext_vector_type(8))) unsigned short u16x8;

__device__ __forceinline__ float fast_exp2(float x) {
#if __has_builtin(__builtin_amdgcn_exp2f)
  return __builtin_amdgcn_exp2f(x);
#else
  return exp2f(x);
#endif
}
__device__ __forceinline__ float fast_rcp(float x) {
#if __has_builtin(__builtin_amdgcn_rcpf)
  return __builtin_amdgcn_rcpf(x);
#else
  return 1.0f / x;
#endif
}
__device__ __forceinline__ float sigm(float x) {
  return fast_rcp(1.0f + fast_exp2(-1.44269504f * x));
}
__device__ __forceinline__ float tanh_(float x) {
  return 1.0f - 2.0f * fast_rcp(1.0f + fast_exp2(2.88539008f * x));
}
__device__ __forceinline__ unsigned short f2bf(float f) {
  unsigned u; __builtin_memcpy(&u, &f, 4);
  u = (u + 0x7FFFu + ((u >> 16) & 1u)) >> 16;  // RNE; finite inputs
  return (unsigned short)u;
}
__device__ __forceinline__ float bf2f(unsigned short h) {
  unsigned u = ((unsigned)h) << 16;
  float f; __builtin_memcpy(&f, &u, 4);
  return f;
}
__device__ __forceinline__ void split_bf(float v, unsigned short& hi, unsigned short& lo) {
  hi = f2bf(v);
  lo = f2bf(v - bf2f(hi));  // v - bf16(v) is exact in fp32
}

// This wave's recurrent-W fragments, split hi+lo.
// Element e of frag (g,kk) holds W[g*128+ub][kk*32 + k0 + e]  (k0=(lane>>4)*8).
// Same (lanegroup,elem)->k permutation as the A-side LDS read => dot products exact.
__device__ __forceinline__ void load_wfrags(const float* __restrict__ W_ih,
                                            const float* __restrict__ W_hh,
                                            bool add_ih, int ub, int k0,
                                            bf16x8 whi[4][4], bf16x8 wlo[4][4]) {
#pragma unroll
  for (int g = 0; g < 4; ++g) {
    const float* ph = W_hh + (size_t)(g * 128 + ub) * H_DIM + k0;
    const float* pi = W_ih + (size_t)(g * 128 + ub) * H_DIM + k0;
#pragma unroll
    for (int kk = 0; kk < 4; ++kk) {
      float4v x0 = *(const float4v*)(ph + kk * 32);
      float4v x1 = *(const float4v*)(ph + kk * 32 + 4);
      if (add_ih) {
        x0 += *(const float4v*)(pi + kk * 32);
        x1 += *(const float4v*)(pi + kk * 32 + 4);
      }
      u16x8 hb, lb;
#pragma unroll
      for (int e = 0; e < 4; ++e) {
        unsigned short h_, l_;
        split_bf(x0[e], h_, l_); hb[e] = h_; lb[e] = l_;
        split_bf(x1[e], h_, l_); hb[e + 4] = h_; lb[e + 4] = l_;
      }
      whi[g][kk] = __builtin_bit_cast(bf16x8, hb);
      wlo[g][kk] = __builtin_bit_cast(bf16x8, lb);
    }
  }
}

__global__ __launch_bounds__(THREADS, 2) void lstm_decoder_kernel(
    const float* __restrict__ latent, const float* __restrict__ fc_w,
    const float* __restrict__ fc_b, const float* __restrict__ W_ih,
    const float* __restrict__ W_hh, const float* __restrict__ b_ih,
    const float* __restrict__ b_hh, const float* __restrict__ Wo,
    const float* __restrict__ bo, const int* __restrict__ seq_len_p,
    float* __restrict__ out) {
  const int tid = threadIdx.x;
  const int lane = tid & 63;
  const int w = tid >> 6;           // wave 0..7
  const int row0 = blockIdx.x * ROWS;
  const int T = seq_len_p[0];

  // h tile: logical [16 rows][128 units] bf16 (hi and lo parts);
  // batch row b lives at matrix row 2b (odd rows stay 0 -> harmless MFMA rows).
  // phys byte = (row*256 + unit*2) ^ ((row&7)<<4)  -> conflict-free ds_read_b128.
  __shared__ __align__(16) unsigned short h_hi[16 * 128];
  __shared__ __align__(16) unsigned short h_lo[16 * 128];

  for (int i = tid; i < 16 * 128; i += THREADS) { h_hi[i] = 0; h_lo[i] = 0; }
  __syncthreads();

  // ---- h0 = latent @ fc_w^T + fc_b ----
  {
    const int u = tid & 127;
    const int rbase = tid >> 7;  // 0..3
#pragma unroll
    for (int pp = 0; pp < 2; ++pp) {
      const int bl = rbase + pp * 4;  // 0..7
      const float4v* lat4 = (const float4v*)(latent + (size_t)(row0 + bl) * L_DIM);
      const float4v* fw4  = (const float4v*)(fc_w + (size_t)u * L_DIM);
      float s = fc_b[u];
#pragma unroll
      for (int j = 0; j < L_DIM / 4; ++j) {
        float4v a = lat4[j], b = fw4[j];
        s += a[0] * b[0] + a[1] * b[1] + a[2] * b[2] + a[3] * b[3];
      }
      const int m = 2 * bl;
      const unsigned off = (unsigned)((m * 256 + u * 2) ^ ((m & 7) << 4));
      unsigned short hh, ll;
      split_bf(s, hh, ll);
      *(unsigned short*)((char*)h_hi + off) = hh;
      *(unsigned short*)((char*)h_lo + off) = ll;
    }
  }

  // ---- per-lane constants ----
  const int ub = (w << 4) + (lane & 15);   // this lane's hidden unit
  const int k0 = (lane >> 4) << 3;
  float bias_g[4];
#pragma unroll
  for (int g = 0; g < 4; ++g) bias_g[g] = b_ih[g * 128 + ub] + b_hh[g * 128 + ub];

  const int ocol = ((w & 3) << 4) + (lane & 15);
  const float bo_l = bo[ocol];

  // Wo fragments, single bf16 (non-recurrent: one-shot ~2^-9 error is fine)
  bf16x8 wofrag[4];
#pragma unroll
  for (int kk = 0; kk < 4; ++kk) {
    const float* p = Wo + (size_t)ocol * H_DIM + k0 + kk * 32;
    float4v x0 = *(const float4v*)p;
    float4v x1 = *(const float4v*)(p + 4);
    u16x8 b;
#pragma unroll
    for (int e = 0; e < 4; ++e) { b[e] = f2bf(x0[e]); b[e + 4] = f2bf(x1[e]); }
    wofrag[kk] = __builtin_bit_cast(bf16x8, b);
  }

  // step-0 weights: W_hh only (x0 = 0)
  bf16x8 whi[4][4], wlo[4][4];
  load_wfrags(W_ih, W_hh, /*add_ih=*/false, ub, k0, whi, wlo);

  __syncthreads();

  // ---- A fragments of current h (row = lane&15, k = kk*32 + (lane>>4)*8 + e) ----
  bf16x8 af_hi[4], af_lo[4];
  const unsigned asw = (unsigned)(((lane & 15) & 7) << 4);
  const unsigned abase = (unsigned)((lane & 15) * 256 + ((lane >> 4) << 4));
  auto read_afrags = [&]() {
#pragma unroll
    for (int kk = 0; kk < 4; ++kk) {
      const unsigned o = (abase + kk * 64) ^ asw;
      af_hi[kk] = *(const bf16x8*)((const char*)h_hi + o);
      af_lo[kk] = *(const bf16x8*)((const char*)h_lo + o);
    }
  };
  read_afrags();  // h_0

  float cA = 0.0f, cB = 0.0f;  // cell state for batch rows 2*lg, 2*lg+1

#pragma unroll 1
  for (int t = 0; t < T; ++t) {
    // gates = h @ W^T + b; split product: hi*Whi + lo*Whi + hi*Wlo
    f32x4 acc[4];
#pragma unroll
    for (int g = 0; g < 4; ++g) {
      f32x4 a = {bias_g[g], bias_g[g], bias_g[g], bias_g[g]};
#pragma unroll
      for (int kk = 0; kk < 4; ++kk)
        a = __builtin_amdgcn_mfma_f32_16x16x32_bf16(af_hi[kk], whi[g][kk], a, 0, 0, 0);
#pragma unroll
      for (int kk = 0; kk < 4; ++kk)
        a = __builtin_amdgcn_mfma_f32_16x16x32_bf16(af_lo[kk], whi[g][kk], a, 0, 0, 0);
#pragma unroll
      for (int kk = 0; kk < 4; ++kk)
        a = __builtin_amdgcn_mfma_f32_16x16x32_bf16(af_hi[kk], wlo[g][kk], a, 0, 0, 0);
      acc[g] = a;
    }

    // element-wise LSTM cell: D reg0 = batch 2*lg, reg2 = batch 2*lg+1
    float hA, hB;
    {
      float si = sigm(acc[0][0]), sf = sigm(acc[1][0]);
      float tg = tanh_(acc[2][0]), so = sigm(acc[3][0]);
      cA = sf * cA + si * tg;
      hA = so * tanh_(cA);
      si = sigm(acc[0][2]); sf = sigm(acc[1][2]);
      tg = tanh_(acc[2][2]); so = sigm(acc[3][2]);
      cB = sf * cB + si * tg;
      hB = so * tanh_(cB);
    }

    __syncthreads();  // everyone is done reading h_t fragments

    {
      const int lg = lane >> 4;
      const int mA = 4 * lg, mB = 4 * lg + 2;
      const unsigned offA = (unsigned)((mA * 256 + ub * 2) ^ ((mA & 7) << 4));
      const unsigned offB = (unsigned)((mB * 256 + ub * 2) ^ ((mB & 7) << 4));
      unsigned short hh, ll;
      split_bf(hA, hh, ll);
      *(unsigned short*)((char*)h_hi + offA) = hh;
      *(unsigned short*)((char*)h_lo + offA) = ll;
      split_bf(hB, hh, ll);
      *(unsigned short*)((char*)h_hi + offB) = hh;
      *(unsigned short*)((char*)h_lo + offB) = ll;
    }

    if (t == 0)  // switch to combined weights for remaining steps
      load_wfrags(W_ih, W_hh, /*add_ih=*/true, ub, k0, whi, wlo);

    __syncthreads();  // h_{t+1} visible
    read_afrags();    // feeds out_t now and gates at t+1

    // out_t = h_{t+1} @ Wo^T + bo  (waves 0-3; fp32 store)
    if (w < 4) {
      f32x4 ao = {bo_l, bo_l, bo_l, bo_l};
#pragma unroll
      for (int kk = 0; kk < 4; ++kk)
        ao = __builtin_amdgcn_mfma_f32_16x16x32_bf16(af_hi[kk], wofrag[kk], ao, 0, 0, 0);
      const int lg = lane >> 4;
      const size_t i0 = ((size_t)(row0 + 2 * lg) * T + t) * O_DIM + ocol;
      const size_t i1 = ((size_t)(row0 + 2 * lg + 1) * T + t) * O_DIM + ocol;
      out[i0] = ao[0];
      out[i1] = ao[2];
    }
  }
}

extern "C" void kernel_launch(void* const* d_in, const int* in_sizes, int n_in,
                              void* d_out, int out_size, void* d_ws, size_t ws_size,
                              hipStream_t stream) {
  const float* latent = (const float*)d_in[0];
  const float* fc_w   = (const float*)d_in[1];
  const float* fc_b   = (const float*)d_in[2];
  const float* W_ih   = (const float*)d_in[3];
  const float* W_hh   = (const float*)d_in[4];
  const float* b_ih   = (const float*)d_in[5];
  const float* b_hh   = (const float*)d_in[6];
  const float* Wo     = (const float*)d_in[7];
  const float* bo     = (const float*)d_in[8];
  const int* seq_len  = (const int*)d_in[9];
  float* out = (float*)d_out;

  const int B = in_sizes[0] / L_DIM;  // 2048
  const int blocks = B / ROWS;        // 256 WGs -> 1 per CU

  hipLaunchKernelGGL(lstm_decoder_kernel, dim3(blocks), dim3(THREADS), 0, stream,
                     latent, fc_w, fc_b, W_ih, W_hh, b_ih, b_hh, Wo, bo, seq_len, out);
}

// Round 3
// 472.368 us; speedup vs baseline: 1.3212x; 1.3212x over previous
//
#include <hip/hip_runtime.h>
#include <hip/hip_bf16.h>

// LSTM decoder: B=2048, L=64, H=128, O=64, T=512.  Output: FLOAT32 [B,T,O].
// Identities:
//   next input x == h  =>  t>=1: gates = h @ (W_ih+W_hh)^T + (b_ih+b_hh)
//   t==0 (x=0):            gates = h0 @ W_hh^T + (b_ih+b_hh)
// Split-bf16 trick using the otherwise-wasted odd MFMA rows:
//   LDS h tile rows: 2b = hi(h_b), 2b+1 = lo(h_b)  (b = local batch 0..7)
//   acc = MFMA(A, Whi, acc); acc = MFMA(A, Wlo, acc)
//   => acc[even] + acc[odd] = (hi+lo)@(Whi+Wlo)  (full ~2^-17 precision, 2 passes)
// One WG per 8 batch rows (256 WGs = 1/CU), weights register-resident,
// h double-buffered in XOR-swizzled LDS (ONE barrier/step), c in fp32 regs.

#define H_DIM 128
#define L_DIM 64
#define O_DIM 64
#define ROWS 8
#define THREADS 512

typedef __attribute__((ext_vector_type(4))) float f32x4;
typedef __attribute__((ext_vector_type(4))) float float4v;
typedef __attribute__((ext_vector_type(8))) __bf16 bf16x8;
typedef __attribute__((ext_vector_type(8))) unsigned short u16x8;

__device__ __forceinline__ float fast_exp2(float x) {
#if __has_builtin(__builtin_amdgcn_exp2f)
  return __builtin_amdgcn_exp2f(x);
#else
  return exp2f(x);
#endif
}
__device__ __forceinline__ float fast_rcp(float x) {
#if __has_builtin(__builtin_amdgcn_rcpf)
  return __builtin_amdgcn_rcpf(x);
#else
  return 1.0f / x;
#endif
}
__device__ __forceinline__ float sigm(float x) {
  return fast_rcp(1.0f + fast_exp2(-1.44269504f * x));
}
__device__ __forceinline__ float tanh_(float x) {
  return 1.0f - 2.0f * fast_rcp(1.0f + fast_exp2(2.88539008f * x));
}
__device__ __forceinline__ unsigned short f2bf(float f) {
  unsigned u; __builtin_memcpy(&u, &f, 4);
  u = (u + 0x7FFFu + ((u >> 16) & 1u)) >> 16;  // RNE; finite inputs
  return (unsigned short)u;
}
__device__ __forceinline__ float bf2f(unsigned short h) {
  unsigned u = ((unsigned)h) << 16;
  float f; __builtin_memcpy(&f, &u, 4);
  return f;
}
__device__ __forceinline__ void split_bf(float v, unsigned short& hi, unsigned short& lo) {
  hi = f2bf(v);
  lo = f2bf(v - bf2f(hi));  // exact residual in fp32
}

// This wave's recurrent-W fragments (hi, lo parts).
// Elem e of frag (g,kk): W[g*128+ub][kk*32 + k0 + e], k0=(lane>>4)*8 —
// same lane->k permutation as the A-side LDS read.
__device__ __forceinline__ void load_wfrags(const float* __restrict__ W_ih,
                                            const float* __restrict__ W_hh,
                                            bool add_ih, int ub, int k0,
                                            bf16x8 whi[4][4], bf16x8 wlo[4][4]) {
#pragma unroll
  for (int g = 0; g < 4; ++g) {
    const float* ph = W_hh + (size_t)(g * 128 + ub) * H_DIM + k0;
    const float* pi = W_ih + (size_t)(g * 128 + ub) * H_DIM + k0;
#pragma unroll
    for (int kk = 0; kk < 4; ++kk) {
      float4v x0 = *(const float4v*)(ph + kk * 32);
      float4v x1 = *(const float4v*)(ph + kk * 32 + 4);
      if (add_ih) {
        x0 += *(const float4v*)(pi + kk * 32);
        x1 += *(const float4v*)(pi + kk * 32 + 4);
      }
      u16x8 hb, lb;
#pragma unroll
      for (int e = 0; e < 4; ++e) {
        unsigned short h_, l_;
        split_bf(x0[e], h_, l_); hb[e] = h_; lb[e] = l_;
        split_bf(x1[e], h_, l_); hb[e + 4] = h_; lb[e + 4] = l_;
      }
      whi[g][kk] = __builtin_bit_cast(bf16x8, hb);
      wlo[g][kk] = __builtin_bit_cast(bf16x8, lb);
    }
  }
}

__global__ __launch_bounds__(THREADS, 2) void lstm_decoder_kernel(
    const float* __restrict__ latent, const float* __restrict__ fc_w,
    const float* __restrict__ fc_b, const float* __restrict__ W_ih,
    const float* __restrict__ W_hh, const float* __restrict__ b_ih,
    const float* __restrict__ b_hh, const float* __restrict__ Wo,
    const float* __restrict__ bo, const int* __restrict__ seq_len_p,
    float* __restrict__ out) {
  const int tid = threadIdx.x;
  const int lane = tid & 63;
  const int w = tid >> 6;            // wave 0..7
  const int row0 = blockIdx.x * ROWS;
  const int T = seq_len_p[0];

  // Double-buffered h tile: [16 rows][128 units] bf16; row 2b=hi, 2b+1=lo.
  // phys byte = (row*256 + unit*2) ^ ((row&7)<<4).
  __shared__ __align__(16) unsigned short hbuf[2][16 * 128];

  // ---- h0 = latent @ fc_w^T + fc_b  -> buf 0 (split rows; fills all 16 rows) ----
  {
    const int u = tid & 127;
    const int rbase = tid >> 7;  // 0..3
#pragma unroll
    for (int pp = 0; pp < 2; ++pp) {
      const int bl = rbase + pp * 4;  // 0..7
      const float4v* lat4 = (const float4v*)(latent + (size_t)(row0 + bl) * L_DIM);
      const float4v* fw4  = (const float4v*)(fc_w + (size_t)u * L_DIM);
      float s = fc_b[u];
#pragma unroll
      for (int j = 0; j < L_DIM / 4; ++j) {
        float4v a = lat4[j], b = fw4[j];
        s += a[0] * b[0] + a[1] * b[1] + a[2] * b[2] + a[3] * b[3];
      }
      const int mh = 2 * bl, ml = 2 * bl + 1;
      unsigned short hh, ll;
      split_bf(s, hh, ll);
      *(unsigned short*)((char*)hbuf[0] + ((unsigned)(mh * 256 + u * 2) ^ ((mh & 7) << 4))) = hh;
      *(unsigned short*)((char*)hbuf[0] + ((unsigned)(ml * 256 + u * 2) ^ ((ml & 7) << 4))) = ll;
    }
  }

  // ---- per-lane constants ----
  const int ub = (w << 4) + (lane & 15);   // this lane's hidden unit
  const int k0 = (lane >> 4) << 3;
  float bias_g[4];
#pragma unroll
  for (int g = 0; g < 4; ++g) bias_g[g] = b_ih[g * 128 + ub] + b_hh[g * 128 + ub];

  const int ocol = ((w & 3) << 4) + (lane & 15);
  const float bo_l = bo[ocol];

  // Wo fragments, single bf16 (A side carries hi+lo -> only Wo rounding remains)
  bf16x8 wofrag[4];
#pragma unroll
  for (int kk = 0; kk < 4; ++kk) {
    const float* p = Wo + (size_t)ocol * H_DIM + k0 + kk * 32;
    float4v x0 = *(const float4v*)p;
    float4v x1 = *(const float4v*)(p + 4);
    u16x8 b;
#pragma unroll
    for (int e = 0; e < 4; ++e) { b[e] = f2bf(x0[e]); b[e + 4] = f2bf(x1[e]); }
    wofrag[kk] = __builtin_bit_cast(bf16x8, b);
  }

  // step-0 weights: W_hh only (x0 = 0)
  bf16x8 whi[4][4], wlo[4][4];
  load_wfrags(W_ih, W_hh, /*add_ih=*/false, ub, k0, whi, wlo);

  __syncthreads();  // h0 visible

  // ---- A fragments (row = lane&15, k = kk*32 + (lane>>4)*8 + e) ----
  bf16x8 af[4];
  const unsigned asw = (unsigned)(((lane & 15) & 7) << 4);
  const unsigned abase = (unsigned)((lane & 15) * 256 + ((lane >> 4) << 4));
  auto read_afrags = [&](const unsigned short* buf) {
#pragma unroll
    for (int kk = 0; kk < 4; ++kk)
      af[kk] = *(const bf16x8*)((const char*)buf + ((abase + kk * 64) ^ asw));
  };
  read_afrags(hbuf[0]);  // h_0

  // write offsets: rows 4lg..4lg+3 = hiA, loA, hiB, loB at column ub
  const int lg = lane >> 4;
  unsigned woff[4];
#pragma unroll
  for (int r = 0; r < 4; ++r) {
    const int m = 4 * lg + r;
    woff[r] = (unsigned)((m * 256 + ub * 2) ^ ((m & 7) << 4));
  }

  float cA = 0.0f, cB = 0.0f;  // cell state for batch rows 2*lg, 2*lg+1
  int p = 0;                   // current h buffer

#pragma unroll 1
  for (int t = 0; t < T; ++t) {
    // gates: 2 MFMA passes over the interleaved hi/lo A tile
    f32x4 acc[4];
#pragma unroll
    for (int g = 0; g < 4; ++g) {
      f32x4 a = {bias_g[g], 0.0f, bias_g[g], 0.0f};
#pragma unroll
      for (int kk = 0; kk < 4; ++kk)
        a = __builtin_amdgcn_mfma_f32_16x16x32_bf16(af[kk], whi[g][kk], a, 0, 0, 0);
#pragma unroll
      for (int kk = 0; kk < 4; ++kk)
        a = __builtin_amdgcn_mfma_f32_16x16x32_bf16(af[kk], wlo[g][kk], a, 0, 0, 0);
      acc[g] = a;
    }

    // element-wise cell: batch 2lg uses regs 0+1, batch 2lg+1 uses regs 2+3
    float hA, hB;
    {
      float gi = acc[0][0] + acc[0][1], gf = acc[1][0] + acc[1][1];
      float gg = acc[2][0] + acc[2][1], go = acc[3][0] + acc[3][1];
      cA = sigm(gf) * cA + sigm(gi) * tanh_(gg);
      hA = sigm(go) * tanh_(cA);
      gi = acc[0][2] + acc[0][3]; gf = acc[1][2] + acc[1][3];
      gg = acc[2][2] + acc[2][3]; go = acc[3][2] + acc[3][3];
      cB = sigm(gf) * cB + sigm(gi) * tanh_(gg);
      hB = sigm(go) * tanh_(cB);
    }

    // write h_{t+1} split into the OTHER buffer (no read/write hazard -> 1 barrier)
    {
      unsigned short hh, ll;
      char* dst = (char*)hbuf[p ^ 1];
      split_bf(hA, hh, ll);
      *(unsigned short*)(dst + woff[0]) = hh;
      *(unsigned short*)(dst + woff[1]) = ll;
      split_bf(hB, hh, ll);
      *(unsigned short*)(dst + woff[2]) = hh;
      *(unsigned short*)(dst + woff[3]) = ll;
    }

    if (t == 0)  // switch to combined weights for remaining steps
      load_wfrags(W_ih, W_hh, /*add_ih=*/true, ub, k0, whi, wlo);

    __syncthreads();          // h_{t+1} visible everywhere
    p ^= 1;
    read_afrags(hbuf[p]);     // h_{t+1}: feeds out_t now, gates at t+1

    // out_t = h_{t+1} @ Wo^T + bo  (waves 0-3; hi+lo rows summed -> full h precision)
    if (w < 4) {
      f32x4 ao = {bo_l, 0.0f, bo_l, 0.0f};
#pragma unroll
      for (int kk = 0; kk < 4; ++kk)
        ao = __builtin_amdgcn_mfma_f32_16x16x32_bf16(af[kk], wofrag[kk], ao, 0, 0, 0);
      const size_t i0 = ((size_t)(row0 + 2 * lg) * T + t) * O_DIM + ocol;
      const size_t i1 = ((size_t)(row0 + 2 * lg + 1) * T + t) * O_DIM + ocol;
      out[i0] = ao[0] + ao[1];
      out[i1] = ao[2] + ao[3];
    }
  }
}

extern "C" void kernel_launch(void* const* d_in, const int* in_sizes, int n_in,
                              void* d_out, int out_size, void* d_ws, size_t ws_size,
                              hipStream_t stream) {
  const float* latent = (const float*)d_in[0];
  const float* fc_w   = (const float*)d_in[1];
  const float* fc_b   = (const float*)d_in[2];
  const float* W_ih   = (const float*)d_in[3];
  const float* W_hh   = (const float*)d_in[4];
  const float* b_ih   = (const float*)d_in[5];
  const float* b_hh   = (const float*)d_in[6];
  const float* Wo     = (const float*)d_in[7];
  const float* bo     = (const float*)d_in[8];
  const int* seq_len  = (const int*)d_in[9];
  float* out = (float*)d_out;

  const int B = in_sizes[0] / L_DIM;  // 2048
  const int blocks = B / ROWS;        // 256 WGs -> 1 per CU

  hipLaunchKernelGGL(lstm_decoder_kernel, dim3(blocks), dim3(THREADS), 0, stream,
                     latent, fc_w, fc_b, W_ih, W_hh, b_ih, b_hh, Wo, bo, seq_len, out);
}

// Round 4
// 340.435 us; speedup vs baseline: 1.8332x; 1.3875x over previous
//
#include <hip/hip_runtime.h>
#include <hip/hip_bf16.h>

// LSTM decoder: B=2048, L=64, H=128, O=64, T=512.  Output: FLOAT32 [B,T,O].
// Identities:
//   next input x == h  =>  t>=1: gates = h @ (W_ih+W_hh)^T + (b_ih+b_hh)
//   t==0 (x=0):            gates = h0 @ W_hh^T + (b_ih+b_hh)
// Precision scheme (single MFMA pass):
//   LDS h tile rows: 2b = hi(h_b), 2b+1 = lo(h_b)   (b = local batch 0..7)
//   acc = MFMA(A_hilo, Whi)  =>  acc[even]+acc[odd] = (hi+lo) @ Whi
//   -> h carries ~2^-17 precision through the recurrence; only W is bf16-rounded
//      (fixed perturbation, damped by sigmoid'/rho<1 -> ~1e-4 drift, OK vs 4.9e-3).
// Gate scales folded into weights/biases at load: i,f,o x log2e ; g x 2*log2e
//   sigma(x) = rcp(1+exp2(-y)),  tanh(x) = 1 - 2*rcp(1+exp2(y))  on pre-scaled y.
// One WG per 8 batch rows (256 WGs = 1/CU), weights register-resident,
// h double-buffered in XOR-swizzled LDS, one barrier per step, c in fp32 regs.

#define H_DIM 128
#define L_DIM 64
#define O_DIM 64
#define ROWS 8
#define THREADS 512
#define LOG2E 1.44269504f

typedef __attribute__((ext_vector_type(4))) float f32x4;
typedef __attribute__((ext_vector_type(4))) float float4v;
typedef __attribute__((ext_vector_type(8))) __bf16 bf16x8;
typedef __attribute__((ext_vector_type(8))) unsigned short u16x8;

__device__ __forceinline__ float fast_exp2(float x) {
#if __has_builtin(__builtin_amdgcn_exp2f)
  return __builtin_amdgcn_exp2f(x);
#else
  return exp2f(x);
#endif
}
__device__ __forceinline__ float fast_rcp(float x) {
#if __has_builtin(__builtin_amdgcn_rcpf)
  return __builtin_amdgcn_rcpf(x);
#else
  return 1.0f / x;
#endif
}
// pre-scaled sigmoid / tanh
__device__ __forceinline__ float sigm_y(float y) {          // y = log2e * x
  return fast_rcp(1.0f + fast_exp2(-y));
}
__device__ __forceinline__ float tanh_y(float y) {          // y = 2*log2e * x
  return 1.0f - 2.0f * fast_rcp(1.0f + fast_exp2(y));
}
// RNE f32->bf16 (used for one-time weight quantization)
__device__ __forceinline__ unsigned short f2bf(float f) {
  unsigned u; __builtin_memcpy(&u, &f, 4);
  u = (u + 0x7FFFu + ((u >> 16) & 1u)) >> 16;
  return (unsigned short)u;
}
// hot-path split via native casts (lo absorbs hi's rounding mode)
__device__ __forceinline__ void split2(float v, unsigned short& hi, unsigned short& lo) {
  __bf16 hb = (__bf16)v;
  __bf16 lb = (__bf16)(v - (float)hb);
  hi = __builtin_bit_cast(unsigned short, hb);
  lo = __builtin_bit_cast(unsigned short, lb);
}

// This wave's recurrent-W fragments (single bf16, gate-scale folded in).
// Elem e of frag (g,kk): gsc[g] * W[g*128+ub][kk*32 + k0 + e], k0=(lane>>4)*8.
__device__ __forceinline__ void load_wfrags(const float* __restrict__ W_ih,
                                            const float* __restrict__ W_hh,
                                            bool add_ih, int ub, int k0,
                                            bf16x8 wf[4][4]) {
  const float gsc[4] = {LOG2E, LOG2E, 2.0f * LOG2E, LOG2E};
#pragma unroll
  for (int g = 0; g < 4; ++g) {
    const float* ph = W_hh + (size_t)(g * 128 + ub) * H_DIM + k0;
    const float* pi = W_ih + (size_t)(g * 128 + ub) * H_DIM + k0;
    const float s = gsc[g];
#pragma unroll
    for (int kk = 0; kk < 4; ++kk) {
      float4v x0 = *(const float4v*)(ph + kk * 32);
      float4v x1 = *(const float4v*)(ph + kk * 32 + 4);
      if (add_ih) {
        x0 += *(const float4v*)(pi + kk * 32);
        x1 += *(const float4v*)(pi + kk * 32 + 4);
      }
      u16x8 b;
#pragma unroll
      for (int e = 0; e < 4; ++e) {
        b[e] = f2bf(s * x0[e]);
        b[e + 4] = f2bf(s * x1[e]);
      }
      wf[g][kk] = __builtin_bit_cast(bf16x8, b);
    }
  }
}

__global__ __launch_bounds__(THREADS, 2) void lstm_decoder_kernel(
    const float* __restrict__ latent, const float* __restrict__ fc_w,
    const float* __restrict__ fc_b, const float* __restrict__ W_ih,
    const float* __restrict__ W_hh, const float* __restrict__ b_ih,
    const float* __restrict__ b_hh, const float* __restrict__ Wo,
    const float* __restrict__ bo, const int* __restrict__ seq_len_p,
    float* __restrict__ out) {
  const int tid = threadIdx.x;
  const int lane = tid & 63;
  const int w = tid >> 6;            // wave 0..7
  const int row0 = blockIdx.x * ROWS;
  const int T = seq_len_p[0];

  // Double-buffered h tile: [16 rows][128 units] bf16; row 2b=hi, 2b+1=lo.
  // phys byte = (row*256 + unit*2) ^ ((row&7)<<4).
  __shared__ __align__(16) unsigned short hbuf[2][16 * 128];

  // ---- h0 = latent @ fc_w^T + fc_b  -> buf 0 ----
  {
    const int u = tid & 127;
    const int rbase = tid >> 7;  // 0..3
#pragma unroll
    for (int pp = 0; pp < 2; ++pp) {
      const int bl = rbase + pp * 4;  // 0..7
      const float4v* lat4 = (const float4v*)(latent + (size_t)(row0 + bl) * L_DIM);
      const float4v* fw4  = (const float4v*)(fc_w + (size_t)u * L_DIM);
      float s = fc_b[u];
#pragma unroll
      for (int j = 0; j < L_DIM / 4; ++j) {
        float4v a = lat4[j], b = fw4[j];
        s += a[0] * b[0] + a[1] * b[1] + a[2] * b[2] + a[3] * b[3];
      }
      const int mh = 2 * bl, ml = 2 * bl + 1;
      unsigned short hh, ll;
      split2(s, hh, ll);
      *(unsigned short*)((char*)hbuf[0] + ((unsigned)(mh * 256 + u * 2) ^ ((mh & 7) << 4))) = hh;
      *(unsigned short*)((char*)hbuf[0] + ((unsigned)(ml * 256 + u * 2) ^ ((ml & 7) << 4))) = ll;
    }
  }

  // ---- per-lane constants ----
  const int ub = (w << 4) + (lane & 15);   // this lane's hidden unit
  const int k0 = (lane >> 4) << 3;
  const float gscb[4] = {LOG2E, LOG2E, 2.0f * LOG2E, LOG2E};
  float bias_g[4];
#pragma unroll
  for (int g = 0; g < 4; ++g)
    bias_g[g] = gscb[g] * (b_ih[g * 128 + ub] + b_hh[g * 128 + ub]);

  const int ocol = ((w & 3) << 4) + (lane & 15);
  const float bo_l = bo[ocol];

  // Wo fragments, single bf16 (A side carries hi+lo)
  bf16x8 wofrag[4];
#pragma unroll
  for (int kk = 0; kk < 4; ++kk) {
    const float* p = Wo + (size_t)ocol * H_DIM + k0 + kk * 32;
    float4v x0 = *(const float4v*)p;
    float4v x1 = *(const float4v*)(p + 4);
    u16x8 b;
#pragma unroll
    for (int e = 0; e < 4; ++e) { b[e] = f2bf(x0[e]); b[e + 4] = f2bf(x1[e]); }
    wofrag[kk] = __builtin_bit_cast(bf16x8, b);
  }

  // step-0 weights: W_hh only (x0 = 0)
  bf16x8 wf[4][4];
  load_wfrags(W_ih, W_hh, /*add_ih=*/false, ub, k0, wf);

  __syncthreads();  // h0 visible

  // ---- A-fragment read (row = lane&15, k = kk*32 + (lane>>4)*8 + e) ----
  bf16x8 af[4];
  const unsigned asw = (unsigned)(((lane & 15) & 7) << 4);
  const unsigned abase = (unsigned)((lane & 15) * 256 + ((lane >> 4) << 4));
#pragma unroll
  for (int kk = 0; kk < 4; ++kk)
    af[kk] = *(const bf16x8*)((const char*)hbuf[0] + ((abase + kk * 64) ^ asw));

  // write offsets: rows 4lg..4lg+3 = hiA, loA, hiB, loB at column ub
  const int lg = lane >> 4;
  unsigned woff[4];
#pragma unroll
  for (int r = 0; r < 4; ++r) {
    const int m = 4 * lg + r;
    woff[r] = (unsigned)((m * 256 + ub * 2) ^ ((m & 7) << 4));
  }

  float cA = 0.0f, cB = 0.0f;  // cell state for batch rows 2*lg, 2*lg+1
  float* pa = out + (size_t)(row0 + 2 * lg) * T * O_DIM + ocol;
  float* pb = out + (size_t)(row0 + 2 * lg + 1) * T * O_DIM + ocol;

  // one LSTM step: gates from af (current h), write new h to dst, re-read af,
  // then emit this step's output from the new h.
  auto halfstep = [&](unsigned short* __restrict__ dst, bool reload) {
    // gates: single MFMA pass; acc[even]+acc[odd] = full-precision h @ W
    f32x4 acc[4];
#pragma unroll
    for (int g = 0; g < 4; ++g) {
      f32x4 a = {bias_g[g], 0.0f, bias_g[g], 0.0f};
#pragma unroll
      for (int kk = 0; kk < 4; ++kk)
        a = __builtin_amdgcn_mfma_f32_16x16x32_bf16(af[kk], wf[g][kk], a, 0, 0, 0);
      acc[g] = a;
    }

    float hA, hB;
    {
      float yi = acc[0][0] + acc[0][1], yf = acc[1][0] + acc[1][1];
      float yg = acc[2][0] + acc[2][1], yo = acc[3][0] + acc[3][1];
      cA = sigm_y(yf) * cA + sigm_y(yi) * tanh_y(yg);
      hA = sigm_y(yo) * tanh_y(2.0f * LOG2E * cA);
      yi = acc[0][2] + acc[0][3]; yf = acc[1][2] + acc[1][3];
      yg = acc[2][2] + acc[2][3]; yo = acc[3][2] + acc[3][3];
      cB = sigm_y(yf) * cB + sigm_y(yi) * tanh_y(yg);
      hB = sigm_y(yo) * tanh_y(2.0f * LOG2E * cB);
    }

    {
      unsigned short hh, ll;
      split2(hA, hh, ll);
      *(unsigned short*)((char*)dst + woff[0]) = hh;
      *(unsigned short*)((char*)dst + woff[1]) = ll;
      split2(hB, hh, ll);
      *(unsigned short*)((char*)dst + woff[2]) = hh;
      *(unsigned short*)((char*)dst + woff[3]) = ll;
    }

    if (reload)  // after step 0: switch to combined (W_ih+W_hh), scaled
      load_wfrags(W_ih, W_hh, /*add_ih=*/true, ub, k0, wf);

    __syncthreads();  // new h visible everywhere

#pragma unroll
    for (int kk = 0; kk < 4; ++kk)
      af[kk] = *(const bf16x8*)((const char*)dst + ((abase + kk * 64) ^ asw));

    // out_t = h_{t+1} @ Wo^T + bo  (waves 0-3)
    if (w < 4) {
      f32x4 ao = {bo_l, 0.0f, bo_l, 0.0f};
#pragma unroll
      for (int kk = 0; kk < 4; ++kk)
        ao = __builtin_amdgcn_mfma_f32_16x16x32_bf16(af[kk], wofrag[kk], ao, 0, 0, 0);
      *pa = ao[0] + ao[1];
      *pb = ao[2] + ao[3];
    }
    pa += O_DIM;
    pb += O_DIM;
  };

#pragma unroll 1
  for (int tt = 0; tt < (T >> 1); ++tt) {
    halfstep(hbuf[1], tt == 0);
    halfstep(hbuf[0], false);
  }
  if (T & 1) halfstep(hbuf[1], T == 1);
}

extern "C" void kernel_launch(void* const* d_in, const int* in_sizes, int n_in,
                              void* d_out, int out_size, void* d_ws, size_t ws_size,
                              hipStream_t stream) {
  const float* latent = (const float*)d_in[0];
  const float* fc_w   = (const float*)d_in[1];
  const float* fc_b   = (const float*)d_in[2];
  const float* W_ih   = (const float*)d_in[3];
  const float* W_hh   = (const float*)d_in[4];
  const float* b_ih   = (const float*)d_in[5];
  const float* b_hh   = (const float*)d_in[6];
  const float* Wo     = (const float*)d_in[7];
  const float* bo     = (const float*)d_in[8];
  const int* seq_len  = (const int*)d_in[9];
  float* out = (float*)d_out;

  const int B = in_sizes[0] / L_DIM;  // 2048
  const int blocks = B / ROWS;        // 256 WGs -> 1 per CU

  hipLaunchKernelGGL(lstm_decoder_kernel, dim3(blocks), dim3(THREADS), 0, stream,
                     latent, fc_w, fc_b, W_ih, W_hh, b_ih, b_hh, Wo, bo, seq_len, out);
}